// Round 7
// baseline (166.348 us; speedup 1.0000x reference)
//
#include <hip/hip_runtime.h>
#include <stdint.h>

#define NELEM 1843200   // 16*128*30*30
#define NPIX  1048576   // 16*64*32*32
#define GRID  512

typedef float v2f __attribute__((ext_vector_type(2)));

// ================= compile-time MT19937 (numpy RandomState(0)) =================
struct RselT { uint32_t v[128]; };
constexpr RselT compute_rsel(){
  uint32_t mt[624] = {};
  mt[0] = 0u;
  for (int i=1;i<624;i++) mt[i] = 1812433253u * (mt[i-1] ^ (mt[i-1] >> 30)) + (uint32_t)i;
  for (int i=0;i<624;i++){
    uint32_t y = (mt[i] & 0x80000000u) | (mt[(i+1)%624] & 0x7fffffffu);
    uint32_t v = mt[(i+397)%624] ^ (y >> 1);
    if (y & 1u) v ^= 0x9908b0dfu;
    mt[i] = v;
  }
  RselT r{};
  for (int k=0;k<128;k++){
    uint32_t z = mt[k];
    z ^= z >> 11;
    z ^= (z << 7)  & 0x9d2c5680u;
    z ^= (z << 15) & 0xefc60000u;
    z ^= z >> 18;
    r.v[k] = z & 63u;   // legacy randint(0,64): one tempered draw, mask 63
  }
  return r;
}
__device__ __constant__ RselT RSEL = compute_rsel();

// ================= threefry2x32 =================
__device__ __forceinline__ uint32_t rotl32(uint32_t x, uint32_t r){ return (x<<r)|(x>>(32u-r)); }

__device__ __forceinline__ void tf2x32(uint32_t k0, uint32_t k1, uint32_t& x0, uint32_t& x1){
  uint32_t ks0=k0, ks1=k1, ks2=k0^k1^0x1BD11BDAu;
  x0 += ks0; x1 += ks1;
#define TFR(r) { x0 += x1; x1 = rotl32(x1,(r)); x1 ^= x0; }
  TFR(13) TFR(15) TFR(26) TFR(6)
  x0 += ks1; x1 += ks2 + 1u;
  TFR(17) TFR(29) TFR(16) TFR(24)
  x0 += ks2; x1 += ks0 + 2u;
  TFR(13) TFR(15) TFR(26) TFR(6)
  x0 += ks0; x1 += ks1 + 3u;
  TFR(17) TFR(29) TFR(16) TFR(24)
  x0 += ks1; x1 += ks2 + 4u;
  TFR(13) TFR(15) TFR(26) TFR(6)
  x0 += ks2; x1 += ks0 + 5u;
#undef TFR
}

struct K2 { uint32_t a, b; };
constexpr uint32_t rotl_c(uint32_t x, int r){ return (x<<r)|(x>>(32-r)); }
constexpr K2 tf_c(uint32_t k0, uint32_t k1, uint32_t x0, uint32_t x1){
  uint32_t ks0=k0, ks1=k1, ks2=k0^k1^0x1BD11BDAu;
  x0 += ks0; x1 += ks1;
#define TFC(r) { x0 += x1; x1 = rotl_c(x1,(r)); x1 ^= x0; }
  TFC(13) TFC(15) TFC(26) TFC(6)
  x0 += ks1; x1 += ks2 + 1u;
  TFC(17) TFC(29) TFC(16) TFC(24)
  x0 += ks2; x1 += ks0 + 2u;
  TFC(13) TFC(15) TFC(26) TFC(6)
  x0 += ks0; x1 += ks1 + 3u;
  TFC(17) TFC(29) TFC(16) TFC(24)
  x0 += ks1; x1 += ks2 + 4u;
  TFC(13) TFC(15) TFC(26) TFC(6)
  x0 += ks2; x1 += ks0 + 5u;
#undef TFC
  return K2{x0, x1};
}
constexpr K2 NK = tf_c(0u, 42u, 0u, 0u);   // noise key
constexpr K2 UK = tf_c(0u, 42u, 0u, 1u);   // uniform key

// raw v_exp_f32 (exp2). Argument guaranteed in [-0.51, 0.51].
__device__ __forceinline__ float exp2_raw(float x){
#if __has_builtin(__builtin_amdgcn_exp2f)
  return __builtin_amdgcn_exp2f(x);
#else
  float r; asm("v_exp_f32 %0, %1" : "=v"(r) : "v"(x)); return r;
#endif
}

// hand-inlined LLVM AMDGPU lowerFEXP f32 path minus unreachable range selects
// (a in [-96.71, 7.2e-7]). Proven bit-identical to expf (R4/R5 absmax).
__device__ __forceinline__ float exp_exact(float a){
#pragma clang fp contract(off)
  const float C  = 0x1.715476p+0f;
  const float CC = 0x1.4ae0bep-26f;
  float ph = a * C;
  float pl = fmaf(a, CC, fmaf(a, C, -ph));
  float e  = __builtin_rintf(ph);
  float A  = (ph - e) + pl;
  return __builtin_ldexpf(exp2_raw(A), (int)e);
}

// ================= XLA f32 erfinv (Giles) =================
__device__ __forceinline__ float erfinv_xla(float x){
#pragma clang fp contract(off)
  float w = -log1pf(-(x*x));
  float p;
  if (w < 5.0f){
    w = w - 2.5f;
    p = 2.81022636e-08f;
    p = 3.43273939e-07f  + p*w;
    p = -3.5233877e-06f  + p*w;
    p = -4.39150654e-06f + p*w;
    p = 0.00021858087f   + p*w;
    p = -0.00125372503f  + p*w;
    p = -0.00417768164f  + p*w;
    p = 0.246640727f     + p*w;
    p = 1.50140941f      + p*w;
  } else {
    w = sqrtf(w) - 3.0f;
    p = -0.000200214257f;
    p = 0.000100950558f  + p*w;
    p = 0.00134934322f   + p*w;
    p = -0.00367342844f  + p*w;
    p = 0.00573950773f   + p*w;
    p = -0.0076224613f   + p*w;
    p = 0.00943887047f   + p*w;
    p = 1.00167406f      + p*w;
    p = 2.83297682f      + p*w;
  }
  return p * x;
}

// ================= XLA/Eigen fast tanh f32 =================
__device__ __forceinline__ float fast_tanh_xla(float x){
  float ax = fabsf(x);
  float cx = fmaxf(fminf(x, 7.90531110763549805f), -7.90531110763549805f);
  float x2 = cx*cx;
  float np_ = fmaf(x2, -2.76076847742355e-16f, 2.00018790482477e-13f);
  np_ = fmaf(x2, np_, -8.60467152213735e-11f);
  np_ = fmaf(x2, np_, 5.12229709037114e-08f);
  np_ = fmaf(x2, np_, 1.48572235717979e-05f);
  np_ = fmaf(x2, np_, 6.37261928875436e-04f);
  np_ = fmaf(x2, np_, 4.89352455891786e-03f);
  float num = cx * np_;
  float dp_ = fmaf(x2, 1.19825839466702e-06f, 1.18534705686654e-04f);
  dp_ = fmaf(x2, dp_, 2.26843463243900e-03f);
  dp_ = fmaf(x2, dp_, 4.89352518554385e-03f);
  return (ax < 0.0004f) ? x : (num / dp_);
}

// ======= device-scope ticket barrier (cnt memset to 0 before each launch) =======
// Release: __syncthreads drains vmcnt; tid0 __threadfence writes back L2 (device
// scope). Acquire: tid0 __threadfence invalidates L1/L2 after the spin.
__device__ __forceinline__ void grid_bar(unsigned* cnt){
  __syncthreads();
  if (threadIdx.x == 0){
    __threadfence();
    unsigned t = atomicAdd(cnt, 1u);
    unsigned target = (t/GRID + 1u)*GRID;
    while (atomicAdd(cnt, 0u) < target) { __builtin_amdgcn_s_sleep(2); }
    __threadfence();
  }
  __syncthreads();
}

// ======================= FUSED persistent kernel =======================
__global__ __launch_bounds__(256, 4) void fused_k(
    const float* __restrict__ inp, const float* __restrict__ ck,
    const float* __restrict__ lut, float* __restrict__ out,
    v2f* __restrict__ lg, uint32_t* __restrict__ sel,
    double* __restrict__ S1, double* __restrict__ S2,
    unsigned* __restrict__ cnt)
{
#pragma clang fp contract(off)
  const int blk = blockIdx.x;      // 0..511
  const int tid = threadIdx.x;
  __shared__ double sh1[4], sh2[4];
  __shared__ float smv[8];
  __shared__ float yl[3600];       // 4 pairs x 900

  // ---- Phase A1: fill lg slice (coalesced, 2048 pixels/block) ----
  #pragma unroll
  for (int q=0;q<8;q++){
    int i = blk*2048 + q*256 + tid;
    float x = inp[i];
    v2f r;
    r[0] = logf(x + 1e-7f);            // relu(x)+eps, x>=0
    r[1] = logf((1.0f - x) + 1e-7f);   // relu(1-x)+eps, x<1
    lg[i] = r;
  }
  // ---- Phase A2: argmax (waves 0,1 -> channels blk, blk+512) ----
  {
    int wv = tid >> 6, lane = tid & 63;
    int c = blk + 512*wv;
    if (wv < 2 && c < 768){
      uint32_t rb = RSEL.v[c/6];
      bool isap = (c % 6) == 0;
      float bv = -3.4e38f; int bi = 0x7fffffff;
      for (int t = lane; t < 576; t += 64){
        float v = ck[c*576 + t] / 0.01f;
        if (isap && (uint32_t)(t/9) == rb) v += 6.0f;
        if (v > bv) { bv = v; bi = t; }
      }
      for (int off=32; off>0; off>>=1){
        float ov = __shfl_xor(bv, off);
        int   oi = __shfl_xor(bi, off);
        if (ov > bv || (ov == bv && oi < bi)) { bv = ov; bi = oi; }
      }
      if (lane == 0) sel[c] = (uint32_t)bi;
    }
  }
  // ---- Phase A3: zero S1(128)+S2(128) contiguous ----
  if (blk == 511) ((double*)S1)[tid] = 0.0;

  grid_bar(cnt);

  // ---- Phase B: LUT core (proven R5 arithmetic), y -> LDS ----
  #pragma unroll 1
  for (int sb=0; sb<4; ++sb){
    const int pair = blk*4 + sb;     // b*128 + d
    const int b = pair >> 7;
    const int d = pair & 127;
    int off6[6];
    #pragma unroll
    for (int j=0;j<6;j++){
      uint32_t t = sel[d*6+j];
      int cc = (int)(t/9u); int rem = (int)(t%9u);
      off6[j] = cc*1024 + (rem/3)*32 + (rem%3);
    }
    const int pbase = b*65536;
    const float* w = lut + d*64;     // wave-uniform -> SGPR
    double acc1 = 0.0, acc2 = 0.0;
    #pragma unroll 1
    for (int q=0;q<4;q++){
      const int p = tid + q*256;
      if (p < 900){
        int ho = p/30, wo = p - ho*30;
        int pix = pbase + ho*32 + wo;
        float lx[6], l1x[6];
        #pragma unroll
        for (int j=0;j<6;j++){
          v2f v = lg[pix + off6[j]];
          lx[j] = v[0]; l1x[j] = v[1];
        }
        // phase-1 DP over even masks (l1x[0..4]); association-exact
        float S5[32];
        S5[0] = 0.0f;
        #pragma unroll
        for (int k=1;k<32;k++){
          const int m = 2*k;
          S5[k] = S5[(m & (m-1)) >> 1] + l1x[5 - __builtin_ctz((unsigned)m)];
        }
        float y = 0.0f;
        #pragma unroll
        for (int k=0;k<32;k++){
          const int m = 2*k;
          float a0 = S5[k];
          float a1 = S5[k] + l1x[5];
          #pragma unroll
          for (int j=0;j<5;j++){
            if (!(m & (32 >> j))){ a0 = a0 + lx[j]; a1 = a1 + lx[j]; }
          }
          a0 = a0 + lx[5];
          float t0 = exp_exact(a0) * w[m];
          float t1 = exp_exact(a1) * w[m+1];
          y = y + t0;
          y = y + t1;
        }
        yl[sb*900 + p] = y;
        acc1 += (double)y;
        acc2 += (double)y * (double)y;
      }
    }
    #pragma unroll
    for (int off=32; off>0; off>>=1){
      acc1 += __shfl_down(acc1, off);
      acc2 += __shfl_down(acc2, off);
    }
    int wid = tid >> 6;
    if ((tid & 63) == 0){ sh1[wid] = acc1; sh2[wid] = acc2; }
    __syncthreads();
    if (tid == 0){
      atomicAdd(&S1[d], sh1[0]+sh1[1]+sh1[2]+sh1[3]);
      atomicAdd(&S2[d], sh2[0]+sh2[1]+sh2[2]+sh2[3]);
    }
    __syncthreads();
  }

  grid_bar(cnt);

  // ---- Phase C: BN finalize (exact f64 math) + noise + quant ----
  if (tid < 4){
    const int dd = (blk*4 + tid) & 127;
    double m = S1[dd] / 14400.0;
    float m32 = (float)m;
    double ey2 = S2[dd] / 14400.0;
    double v = ey2 - 2.0*(double)m32*m + (double)m32*(double)m32;
    smv[tid*2+0] = m32;
    smv[tid*2+1] = (float)v;
  }
  __syncthreads();
  #pragma unroll 1
  for (int sb=0; sb<4; ++sb){
    const int pair = blk*4 + sb;
    const float m32 = smv[sb*2+0], var32 = smv[sb*2+1];
    #pragma unroll 1
    for (int q=0;q<4;q++){
      const int p = tid + q*256;
      if (p >= 900) continue;
      const int i = pair*900 + p;
      float y = (yl[sb*900 + p] - m32) / sqrtf(var32 + 1e-5f);
      { uint32_t x0 = 0u, x1 = (uint32_t)i; tf2x32(NK.a, NK.b, x0, x1);
        uint32_t nb = x0 ^ x1;
        float u01 = __uint_as_float((nb >> 9) | 0x3f800000u) - 1.0f;
        const float lo = __uint_as_float(0xBF7FFFFFu);
        float un = u01 * 2.0f + lo;
        un = fmaxf(lo, un);
        float noise = __uint_as_float(0x3FB504F3u) * erfinv_xla(un);
        y = y + noise * 0.2f;
      }
      out[i] = y;
      uint32_t x0 = 0u, x1 = (uint32_t)i;
      tf2x32(UK.a, UK.b, x0, x1);
      uint32_t rb = x0 ^ x1;
      float r = __uint_as_float((rb >> 9) | 0x3f800000u) - 1.0f;
      float s = 0.5f + 0.5f * fast_tanh_xla(0.5f * y);
      out[NELEM + i] = (s > r) ? 1.0f : 0.0f;
    }
  }
}

// ======================= fallback (R5, proven) kernels =======================
__global__ __launch_bounds__(64) void argmax_k(const float* __restrict__ ck,
    uint32_t* __restrict__ sel, double* __restrict__ Sz){
  int o = blockIdx.x;
  int lane = threadIdx.x;
  if (o == 0){
    #pragma unroll
    for (int q=0;q<4;q++) Sz[lane*4+q] = 0.0;
  }
  uint32_t rb = RSEL.v[o/6];
  bool isap = (o % 6) == 0;
  float bv = -3.4e38f; int bi = 0x7fffffff;
  for (int t = lane; t < 576; t += 64){
    float v = ck[o*576 + t] / 0.01f;
    if (isap && (uint32_t)(t/9) == rb) v += 6.0f;
    if (v > bv) { bv = v; bi = t; }
  }
  for (int off=32; off>0; off>>=1){
    float ov = __shfl_xor(bv, off);
    int   oi = __shfl_xor(bi, off);
    if (ov > bv || (ov == bv && oi < bi)) { bv = ov; bi = oi; }
  }
  if (lane == 0) sel[o] = (uint32_t)bi;
}

__global__ __launch_bounds__(256) void c1_k(const float* __restrict__ inp,
    const float* __restrict__ lut, const uint32_t* __restrict__ sel,
    float* __restrict__ yraw, double* __restrict__ S1, double* __restrict__ S2){
#pragma clang fp contract(off)
  const int blk = blockIdx.x;
  const int b = blk >> 7;
  const int d = blk & 127;
  int off6[6];
  #pragma unroll
  for (int j=0;j<6;j++){
    uint32_t t = sel[d*6+j];
    int cc = (int)(t/9u); int rem = (int)(t%9u);
    off6[j] = cc*1024 + (rem/3)*32 + (rem%3);
  }
  const int pbase = b*65536;
  const float* w = lut + d*64;
  double acc1 = 0.0, acc2 = 0.0;
  #pragma unroll 1
  for (int p = threadIdx.x; p < 900; p += 256){
    int ho = p/30, wo = p - ho*30;
    int pix = pbase + ho*32 + wo;
    float lx[6], l1x[6];
    #pragma unroll
    for (int j=0;j<6;j++){
      float x = inp[pix + off6[j]];
      lx[j]  = logf(x + 1e-7f);
      l1x[j] = logf((1.0f - x) + 1e-7f);
    }
    float S5[32];
    S5[0] = 0.0f;
    #pragma unroll
    for (int k=1;k<32;k++){
      const int m = 2*k;
      S5[k] = S5[(m & (m-1)) >> 1] + l1x[5 - __builtin_ctz((unsigned)m)];
    }
    float y = 0.0f;
    #pragma unroll
    for (int k=0;k<32;k++){
      const int m = 2*k;
      float a0 = S5[k];
      float a1 = S5[k] + l1x[5];
      #pragma unroll
      for (int j=0;j<5;j++){
        if (!(m & (32 >> j))){ a0 = a0 + lx[j]; a1 = a1 + lx[j]; }
      }
      a0 = a0 + lx[5];
      float t0 = exp_exact(a0) * w[m];
      float t1 = exp_exact(a1) * w[m+1];
      y = y + t0;
      y = y + t1;
    }
    yraw[blk*900 + p] = y;
    acc1 += (double)y;
    acc2 += (double)y * (double)y;
  }
  #pragma unroll
  for (int off=32; off>0; off>>=1){
    acc1 += __shfl_down(acc1, off);
    acc2 += __shfl_down(acc2, off);
  }
  __shared__ double sh1[4], sh2[4];
  int wid = threadIdx.x >> 6;
  if ((threadIdx.x & 63) == 0){ sh1[wid] = acc1; sh2[wid] = acc2; }
  __syncthreads();
  if (threadIdx.x == 0){
    atomicAdd(&S1[d], sh1[0]+sh1[1]+sh1[2]+sh1[3]);
    atomicAdd(&S2[d], sh2[0]+sh2[1]+sh2[2]+sh2[3]);
  }
}

__global__ __launch_bounds__(256) void c3_k(float* __restrict__ out,
    const double* __restrict__ S1, const double* __restrict__ S2){
#pragma clang fp contract(off)
  const int base = blockIdx.x * 256;
  __shared__ float smv[4];
  const int dA = (base / 900) & 127;
  const int dB = ((base + 255) / 900) & 127;
  if (threadIdx.x < 2){
    int dd = threadIdx.x ? dB : dA;
    double m = S1[dd] / 14400.0;
    float m32 = (float)m;
    double ey2 = S2[dd] / 14400.0;
    double v = ey2 - 2.0*(double)m32*m + (double)m32*(double)m32;
    smv[threadIdx.x*2+0] = m32;
    smv[threadIdx.x*2+1] = (float)v;
  }
  __syncthreads();
  const int i = base + threadIdx.x;
  const int d = (i / 900) & 127;
  const int sb = (d != dA) ? 2 : 0;
  const float m32 = smv[sb], var32 = smv[sb+1];

  float yr = out[NELEM + i];
  float y = (yr - m32) / sqrtf(var32 + 1e-5f);

  { uint32_t x0 = 0u, x1 = (uint32_t)i; tf2x32(NK.a, NK.b, x0, x1);
    uint32_t nb = x0 ^ x1;
    float u01 = __uint_as_float((nb >> 9) | 0x3f800000u) - 1.0f;
    const float lo = __uint_as_float(0xBF7FFFFFu);
    float un = u01 * 2.0f + lo;
    un = fmaxf(lo, un);
    float noise = __uint_as_float(0x3FB504F3u) * erfinv_xla(un);
    y = y + noise * 0.2f;
  }
  out[i] = y;

  uint32_t x0 = 0u, x1 = (uint32_t)i;
  tf2x32(UK.a, UK.b, x0, x1);
  uint32_t rb = x0 ^ x1;
  float r = __uint_as_float((rb >> 9) | 0x3f800000u) - 1.0f;

  float s = 0.5f + 0.5f * fast_tanh_xla(0.5f * y);
  out[NELEM + i] = (s > r) ? 1.0f : 0.0f;
}

extern "C" void kernel_launch(void* const* d_in, const int* in_sizes, int n_in,
                              void* d_out, int out_size, void* d_ws, size_t ws_size,
                              hipStream_t stream) {
  (void)in_sizes; (void)n_in; (void)out_size;
  const float* inp = (const float*)d_in[0];
  const float* ck  = (const float*)d_in[1];
  const float* lut = (const float*)d_in[2];
  float* out = (float*)d_out;

  uint32_t* sel = (uint32_t*)d_ws;                   // 768 u32 @ 0
  unsigned* cnt = (unsigned*)((char*)d_ws + 3072);   // barrier counter
  double*   S1  = (double*)((char*)d_ws + 4096);     // 128
  double*   S2  = S1 + 128;                          // 128 (contiguous)
  v2f*      lg  = (v2f*)((char*)d_ws + 8192);        // NPIX float2 = 8 MiB

  const size_t ws_need = 8192 + (size_t)NPIX * 8;

  if (ws_size >= ws_need){
    hipMemsetAsync(cnt, 0, 4, stream);   // barrier tickets start at 0 every call
    hipLaunchKernelGGL(fused_k, dim3(GRID), dim3(256), 0, stream,
                       inp, ck, lut, out, lg, sel, S1, S2, cnt);
  } else {
    hipLaunchKernelGGL(argmax_k, dim3(768),  dim3(64),  0, stream, ck, sel, S1);
    hipLaunchKernelGGL(c1_k,     dim3(2048), dim3(256), 0, stream, inp, lut, sel, out + NELEM, S1, S2);
    hipLaunchKernelGGL(c3_k,     dim3(7200), dim3(256), 0, stream, out, S1, S2);
  }
}

// Round 8
// 78.468 us; speedup vs baseline: 2.1200x; 2.1200x over previous
//
#include <hip/hip_runtime.h>
#include <stdint.h>

#define NELEM 1843200   // 16*128*30*30
#define NPIX  1048576   // 16*64*32*32

typedef float v2f __attribute__((ext_vector_type(2)));

// ================= compile-time MT19937 (numpy RandomState(0)) =================
struct RselT { uint32_t v[128]; };
constexpr RselT compute_rsel(){
  uint32_t mt[624] = {};
  mt[0] = 0u;
  for (int i=1;i<624;i++) mt[i] = 1812433253u * (mt[i-1] ^ (mt[i-1] >> 30)) + (uint32_t)i;
  for (int i=0;i<624;i++){
    uint32_t y = (mt[i] & 0x80000000u) | (mt[(i+1)%624] & 0x7fffffffu);
    uint32_t v = mt[(i+397)%624] ^ (y >> 1);
    if (y & 1u) v ^= 0x9908b0dfu;
    mt[i] = v;
  }
  RselT r{};
  for (int k=0;k<128;k++){
    uint32_t z = mt[k];
    z ^= z >> 11;
    z ^= (z << 7)  & 0x9d2c5680u;
    z ^= (z << 15) & 0xefc60000u;
    z ^= z >> 18;
    r.v[k] = z & 63u;   // legacy randint(0,64): one tempered draw, mask 63
  }
  return r;
}
__device__ __constant__ RselT RSEL = compute_rsel();

// ================= threefry2x32 =================
__device__ __forceinline__ uint32_t rotl32(uint32_t x, uint32_t r){ return (x<<r)|(x>>(32u-r)); }

__device__ __forceinline__ void tf2x32(uint32_t k0, uint32_t k1, uint32_t& x0, uint32_t& x1){
  uint32_t ks0=k0, ks1=k1, ks2=k0^k1^0x1BD11BDAu;
  x0 += ks0; x1 += ks1;
#define TFR(r) { x0 += x1; x1 = rotl32(x1,(r)); x1 ^= x0; }
  TFR(13) TFR(15) TFR(26) TFR(6)
  x0 += ks1; x1 += ks2 + 1u;
  TFR(17) TFR(29) TFR(16) TFR(24)
  x0 += ks2; x1 += ks0 + 2u;
  TFR(13) TFR(15) TFR(26) TFR(6)
  x0 += ks0; x1 += ks1 + 3u;
  TFR(17) TFR(29) TFR(16) TFR(24)
  x0 += ks1; x1 += ks2 + 4u;
  TFR(13) TFR(15) TFR(26) TFR(6)
  x0 += ks2; x1 += ks0 + 5u;
#undef TFR
}

struct K2 { uint32_t a, b; };
constexpr uint32_t rotl_c(uint32_t x, int r){ return (x<<r)|(x>>(32-r)); }
constexpr K2 tf_c(uint32_t k0, uint32_t k1, uint32_t x0, uint32_t x1){
  uint32_t ks0=k0, ks1=k1, ks2=k0^k1^0x1BD11BDAu;
  x0 += ks0; x1 += ks1;
#define TFC(r) { x0 += x1; x1 = rotl_c(x1,(r)); x1 ^= x0; }
  TFC(13) TFC(15) TFC(26) TFC(6)
  x0 += ks1; x1 += ks2 + 1u;
  TFC(17) TFC(29) TFC(16) TFC(24)
  x0 += ks2; x1 += ks0 + 2u;
  TFC(13) TFC(15) TFC(26) TFC(6)
  x0 += ks0; x1 += ks1 + 3u;
  TFC(17) TFC(29) TFC(16) TFC(24)
  x0 += ks1; x1 += ks2 + 4u;
  TFC(13) TFC(15) TFC(26) TFC(6)
  x0 += ks2; x1 += ks0 + 5u;
#undef TFC
  return K2{x0, x1};
}
constexpr K2 NK = tf_c(0u, 42u, 0u, 0u);   // noise key
constexpr K2 UK = tf_c(0u, 42u, 0u, 1u);   // uniform key

// raw v_exp_f32 (exp2). Argument guaranteed in [-0.51, 0.51].
__device__ __forceinline__ float exp2_raw(float x){
#if __has_builtin(__builtin_amdgcn_exp2f)
  return __builtin_amdgcn_exp2f(x);
#else
  float r; asm("v_exp_f32 %0, %1" : "=v"(r) : "v"(x)); return r;
#endif
}

// hand-inlined LLVM AMDGPU lowerFEXP f32 path minus unreachable range selects
// (a in [-96.71, 7.2e-7]). Proven bit-identical to expf (R4-R7 absmax).
__device__ __forceinline__ float exp_exact(float a){
#pragma clang fp contract(off)
  const float C  = 0x1.715476p+0f;
  const float CC = 0x1.4ae0bep-26f;
  float ph = a * C;
  float pl = fmaf(a, CC, fmaf(a, C, -ph));
  float e  = __builtin_rintf(ph);
  float A  = (ph - e) + pl;
  return __builtin_ldexpf(exp2_raw(A), (int)e);
}

// ================= XLA f32 erfinv (Giles) =================
__device__ __forceinline__ float erfinv_xla(float x){
#pragma clang fp contract(off)
  float w = -log1pf(-(x*x));
  float p;
  if (w < 5.0f){
    w = w - 2.5f;
    p = 2.81022636e-08f;
    p = 3.43273939e-07f  + p*w;
    p = -3.5233877e-06f  + p*w;
    p = -4.39150654e-06f + p*w;
    p = 0.00021858087f   + p*w;
    p = -0.00125372503f  + p*w;
    p = -0.00417768164f  + p*w;
    p = 0.246640727f     + p*w;
    p = 1.50140941f      + p*w;
  } else {
    w = sqrtf(w) - 3.0f;
    p = -0.000200214257f;
    p = 0.000100950558f  + p*w;
    p = 0.00134934322f   + p*w;
    p = -0.00367342844f  + p*w;
    p = 0.00573950773f   + p*w;
    p = -0.0076224613f   + p*w;
    p = 0.00943887047f   + p*w;
    p = 1.00167406f      + p*w;
    p = 2.83297682f      + p*w;
  }
  return p * x;
}

// ================= XLA/Eigen fast tanh f32 =================
__device__ __forceinline__ float fast_tanh_xla(float x){
  float ax = fabsf(x);
  float cx = fmaxf(fminf(x, 7.90531110763549805f), -7.90531110763549805f);
  float x2 = cx*cx;
  float np_ = fmaf(x2, -2.76076847742355e-16f, 2.00018790482477e-13f);
  np_ = fmaf(x2, np_, -8.60467152213735e-11f);
  np_ = fmaf(x2, np_, 5.12229709037114e-08f);
  np_ = fmaf(x2, np_, 1.48572235717979e-05f);
  np_ = fmaf(x2, np_, 6.37261928875436e-04f);
  np_ = fmaf(x2, np_, 4.89352455891786e-03f);
  float num = cx * np_;
  float dp_ = fmaf(x2, 1.19825839466702e-06f, 1.18534705686654e-04f);
  dp_ = fmaf(x2, dp_, 2.26843463243900e-03f);
  dp_ = fmaf(x2, dp_, 4.89352518554385e-03f);
  return (ax < 0.0004f) ? x : (num / dp_);
}

// ========== prep: lg fill (blocks 0..4095) + argmax (4096..4287) + zero (4288) ==========
__global__ __launch_bounds__(256) void prep_k(const float* __restrict__ inp,
    const float* __restrict__ ck, v2f* __restrict__ lg,
    uint32_t* __restrict__ sel, double* __restrict__ Sz){
  const int blk = blockIdx.x;
  const int tid = threadIdx.x;
  if (blk < 4096){
    int i = blk*256 + tid;
    float x = inp[i];
    v2f r;
    r[0] = logf(x + 1e-7f);            // relu(x)+eps, x>=0
    r[1] = logf((1.0f - x) + 1e-7f);   // relu(1-x)+eps, x<1
    lg[i] = r;
  } else if (blk < 4288){
    // 4 waves x 1 channel each
    int o = (blk - 4096)*4 + (tid >> 6);   // 0..767
    int lane = tid & 63;
    uint32_t rb = RSEL.v[o/6];
    bool isap = (o % 6) == 0;
    float bv = -3.4e38f; int bi = 0x7fffffff;
    for (int t = lane; t < 576; t += 64){
      float v = ck[o*576 + t] / 0.01f;
      if (isap && (uint32_t)(t/9) == rb) v += 6.0f;
      if (v > bv) { bv = v; bi = t; }
    }
    for (int off=32; off>0; off>>=1){
      float ov = __shfl_xor(bv, off);
      int   oi = __shfl_xor(bi, off);
      if (ov > bv || (ov == bv && oi < bi)) { bv = ov; bi = oi; }
    }
    if (lane == 0) sel[o] = (uint32_t)bi;
  } else {
    Sz[tid] = 0.0;   // 256 doubles = S1(128)+S2(128)
  }
}

// ================= gather-conv + LUT layer, f64 channel stats =================
// DFS-prefix form: 5 nested unrolled loops carry s0..s4 (5 live regs instead of
// S5[32]); identical 31 adds in identical order, leaves visited m-ascending ->
// bit-identical to the R5 DP (chain adds l1x[j] ascending j, then the a0/a1
// tails exactly as before).
template<int PRE>
__global__ __launch_bounds__(256) void c1_k(const float* __restrict__ inp,
    const v2f* __restrict__ lg,
    const float* __restrict__ lut, const uint32_t* __restrict__ sel,
    float* __restrict__ yraw, double* __restrict__ S1, double* __restrict__ S2){
#pragma clang fp contract(off)
  const int blk = blockIdx.x;      // b*128 + d
  const int b = blk >> 7;
  const int d = blk & 127;
  int off6[6];
  #pragma unroll
  for (int j=0;j<6;j++){
    uint32_t t = sel[d*6+j];
    int cc = (int)(t/9u); int rem = (int)(t%9u);
    off6[j] = cc*1024 + (rem/3)*32 + (rem%3);
  }
  const int pbase = b*65536;
  const float* w = lut + d*64;     // wave-uniform -> SGPR
  double acc1 = 0.0, acc2 = 0.0;
  #pragma unroll 1
  for (int p = threadIdx.x; p < 900; p += 256){
    int ho = p/30, wo = p - ho*30;
    int pix = pbase + ho*32 + wo;
    float lx[6], l1x[6];
    #pragma unroll
    for (int j=0;j<6;j++){
      if (PRE){
        v2f v = lg[pix + off6[j]];
        lx[j] = v[0]; l1x[j] = v[1];
      } else {
        float x = inp[pix + off6[j]];
        lx[j]  = logf(x + 1e-7f);
        l1x[j] = logf((1.0f - x) + 1e-7f);
      }
    }
    float y = 0.0f;
    #pragma unroll
    for (int b0=0;b0<2;b0++){
      float s0 = b0 ? (0.0f + l1x[0]) : 0.0f;
      #pragma unroll
      for (int b1=0;b1<2;b1++){
        float s1 = b1 ? (s0 + l1x[1]) : s0;
        #pragma unroll
        for (int b2=0;b2<2;b2++){
          float s2 = b2 ? (s1 + l1x[2]) : s1;
          #pragma unroll
          for (int b3=0;b3<2;b3++){
            float s3 = b3 ? (s2 + l1x[3]) : s2;
            #pragma unroll
            for (int b4=0;b4<2;b4++){
              float s4 = b4 ? (s3 + l1x[4]) : s3;
              const int m = b0*32 + b1*16 + b2*8 + b3*4 + b4*2;
              float a0 = s4;
              float a1 = s4 + l1x[5];
              #pragma unroll
              for (int j=0;j<5;j++){
                if (!(m & (32 >> j))){ a0 = a0 + lx[j]; a1 = a1 + lx[j]; }
              }
              a0 = a0 + lx[5];
              float t0 = exp_exact(a0) * w[m];
              float t1 = exp_exact(a1) * w[m+1];
              y = y + t0;       // strict i-ascending sum
              y = y + t1;
            }
          }
        }
      }
    }
    yraw[blk*900 + p] = y;
    acc1 += (double)y;
    acc2 += (double)y * (double)y;
  }
  #pragma unroll
  for (int off=32; off>0; off>>=1){
    acc1 += __shfl_down(acc1, off);
    acc2 += __shfl_down(acc2, off);
  }
  __shared__ double sh1[4], sh2[4];
  int wid = threadIdx.x >> 6;
  if ((threadIdx.x & 63) == 0){ sh1[wid] = acc1; sh2[wid] = acc2; }
  __syncthreads();
  if (threadIdx.x == 0){
    atomicAdd(&S1[d], sh1[0]+sh1[1]+sh1[2]+sh1[3]);
    atomicAdd(&S2[d], sh2[0]+sh2[1]+sh2[2]+sh2[3]);
  }
}

// ================= BN finalize + normalize + noise + stochastic quant =================
__global__ __launch_bounds__(256) void c3_k(float* __restrict__ out,
    const double* __restrict__ S1, const double* __restrict__ S2){
#pragma clang fp contract(off)
  const int base = blockIdx.x * 256;
  __shared__ float smv[4];
  const int dA = (base / 900) & 127;
  const int dB = ((base + 255) / 900) & 127;
  if (threadIdx.x < 2){
    int dd = threadIdx.x ? dB : dA;
    double m = S1[dd] / 14400.0;
    float m32 = (float)m;
    double ey2 = S2[dd] / 14400.0;
    double v = ey2 - 2.0*(double)m32*m + (double)m32*(double)m32;
    smv[threadIdx.x*2+0] = m32;
    smv[threadIdx.x*2+1] = (float)v;
  }
  __syncthreads();
  const int i = base + threadIdx.x;   // NELEM = 7200*256 exactly, no tail
  const int d = (i / 900) & 127;
  const int sb = (d != dA) ? 2 : 0;
  const float m32 = smv[sb], var32 = smv[sb+1];

  float yr = out[NELEM + i];
  float y = (yr - m32) / sqrtf(var32 + 1e-5f);

  { uint32_t x0 = 0u, x1 = (uint32_t)i; tf2x32(NK.a, NK.b, x0, x1);
    uint32_t nb = x0 ^ x1;
    float u01 = __uint_as_float((nb >> 9) | 0x3f800000u) - 1.0f;
    const float lo = __uint_as_float(0xBF7FFFFFu);
    float un = u01 * 2.0f + lo;
    un = fmaxf(lo, un);
    float noise = __uint_as_float(0x3FB504F3u) * erfinv_xla(un);
    y = y + noise * 0.2f;
  }
  out[i] = y;

  uint32_t x0 = 0u, x1 = (uint32_t)i;
  tf2x32(UK.a, UK.b, x0, x1);
  uint32_t rb = x0 ^ x1;
  float r = __uint_as_float((rb >> 9) | 0x3f800000u) - 1.0f;

  float s = 0.5f + 0.5f * fast_tanh_xla(0.5f * y);
  out[NELEM + i] = (s > r) ? 1.0f : 0.0f;
}

// ================= fallback argmax (no-ws path) =================
__global__ __launch_bounds__(64) void argmax_k(const float* __restrict__ ck,
    uint32_t* __restrict__ sel, double* __restrict__ Sz){
  int o = blockIdx.x;
  int lane = threadIdx.x;
  if (o == 0){
    #pragma unroll
    for (int q=0;q<4;q++) Sz[lane*4+q] = 0.0;
  }
  uint32_t rb = RSEL.v[o/6];
  bool isap = (o % 6) == 0;
  float bv = -3.4e38f; int bi = 0x7fffffff;
  for (int t = lane; t < 576; t += 64){
    float v = ck[o*576 + t] / 0.01f;
    if (isap && (uint32_t)(t/9) == rb) v += 6.0f;
    if (v > bv) { bv = v; bi = t; }
  }
  for (int off=32; off>0; off>>=1){
    float ov = __shfl_xor(bv, off);
    int   oi = __shfl_xor(bi, off);
    if (ov > bv || (ov == bv && oi < bi)) { bv = ov; bi = oi; }
  }
  if (lane == 0) sel[o] = (uint32_t)bi;
}

extern "C" void kernel_launch(void* const* d_in, const int* in_sizes, int n_in,
                              void* d_out, int out_size, void* d_ws, size_t ws_size,
                              hipStream_t stream) {
  (void)in_sizes; (void)n_in; (void)out_size;
  const float* inp = (const float*)d_in[0];
  const float* ck  = (const float*)d_in[1];
  const float* lut = (const float*)d_in[2];
  float* out = (float*)d_out;

  uint32_t* sel = (uint32_t*)d_ws;                   // 768 u32
  double*   S1  = (double*)((char*)d_ws + 4096);     // 128
  double*   S2  = S1 + 128;                          // 128 (contiguous)
  v2f*      lg  = (v2f*)((char*)d_ws + 8192);        // NPIX float2 = 8 MiB

  const size_t ws_need = 8192 + (size_t)NPIX * 8;

  if (ws_size >= ws_need){
    hipLaunchKernelGGL(prep_k,  dim3(4289), dim3(256), 0, stream, inp, ck, lg, sel, S1);
    hipLaunchKernelGGL(c1_k<1>, dim3(2048), dim3(256), 0, stream, inp, lg, lut, sel, out + NELEM, S1, S2);
  } else {
    hipLaunchKernelGGL(argmax_k, dim3(768), dim3(64), 0, stream, ck, sel, S1);
    hipLaunchKernelGGL(c1_k<0>, dim3(2048), dim3(256), 0, stream, inp, lg, lut, sel, out + NELEM, S1, S2);
  }
  hipLaunchKernelGGL(c3_k, dim3(7200), dim3(256), 0, stream, out, S1, S2);
}